// Round 6
// baseline (2732.325 us; speedup 1.0000x reference)
//
#include <hip/hip_runtime.h>

typedef __bf16 bf16_t;
typedef __bf16 bf16x8 __attribute__((ext_vector_type(8)));
typedef float f32x4 __attribute__((ext_vector_type(4)));
typedef __fp16 f16x2 __attribute__((ext_vector_type(2)));
typedef int i32x4 __attribute__((ext_vector_type(4)));

#define EPSBN 1e-5f

__device__ __forceinline__ void gload16(const void* g, void* l) {
  __builtin_amdgcn_global_load_lds(
      (const __attribute__((address_space(1))) void*)g,
      (__attribute__((address_space(3))) void*)l, 16, 0, 0);
}

__device__ __forceinline__ f16x2 i2h(int x) { union { int i; f16x2 h; } u; u.i = x; return u.h; }
__device__ __forceinline__ int h2i(f16x2 x) { union { int i; f16x2 h; } u; u.h = x; return u.i; }

__device__ __forceinline__ float dot2i(int w, int h, float acc) {
#if __has_builtin(__builtin_amdgcn_fdot2)
  return __builtin_amdgcn_fdot2(i2h(w), i2h(h), acc, false);
#else
  f16x2 a = i2h(w), b = i2h(h);
  return acc + (float)a[0] * (float)b[0] + (float)a[1] * (float)b[1];
#endif
}

// ---------------- weight packing: fp32 -> bf16 (w1 padded 20->32 ch) ----------------
__global__ __launch_bounds__(256) void pack_w_kernel(
    const float* __restrict__ w1, const float* __restrict__ w2,
    const float* __restrict__ w3, const float* __restrict__ w4,
    const float* __restrict__ w5,
    bf16_t* __restrict__ p1, bf16_t* __restrict__ p2, bf16_t* __restrict__ p3,
    bf16_t* __restrict__ p4, bf16_t* __restrict__ p5)
{
  const int idx = blockIdx.x * 256 + threadIdx.x;
  switch (blockIdx.y) {
    case 0:
      if (idx < 256 * 160) {
        int o = idx / 160, k = idx % 160, tap = k / 32, ch = k % 32;
        p1[idx] = (bf16_t)((ch < 20) ? w1[o * 100 + tap * 20 + ch] : 0.0f);
      }
      break;
    case 1: if (idx < 512 * 1280) p2[idx] = (bf16_t)w2[idx]; break;
    case 2: if (idx < 256 * 2560) p3[idx] = (bf16_t)w3[idx]; break;
    case 3: if (idx < 128 * 768)  p4[idx] = (bf16_t)w4[idx]; break;
    default: if (idx < 128 * 384) p5[idx] = (bf16_t)w5[idx]; break;
  }
}

// ---------------- x: (B,20,L) fp32 -> (B,L,32) bf16, zero-padded channels ----------------
__global__ __launch_bounds__(256) void pack_x_kernel(
    const float* __restrict__ x, bf16_t* __restrict__ xp)
{
  __shared__ __align__(16) bf16_t Ls[256 * 32];
  const int tid = threadIdx.x;
  const int b = blockIdx.y;
  const int l0 = blockIdx.x * 256;
  bf16x8 z = {};
  #pragma unroll
  for (int i = 0; i < 4; ++i) ((bf16x8*)Ls)[tid + i * 256] = z;
  __syncthreads();
  #pragma unroll
  for (int ch = 0; ch < 20; ++ch) {
    float v = x[((size_t)b * 20 + ch) * 4096 + l0 + tid];
    Ls[tid * 32 + ch] = (bf16_t)v;
  }
  __syncthreads();
  bf16x8* dst = (bf16x8*)(xp + ((size_t)b * 4096 + l0) * 32);
  #pragma unroll
  for (int i = 0; i < 4; ++i) dst[tid + i * 256] = ((bf16x8*)Ls)[tid + i * 256];
}

// ---------------- TDNN layer as MFMA GEMM over dilated taps ----------------
template <int DIN, int C, int DIL, bool OUTF32>
__global__ __launch_bounds__(256, 2) void tdnn_gemm(
    const bf16_t* __restrict__ X, const bf16_t* __restrict__ W,
    const float* __restrict__ bias, const float* __restrict__ gg,
    const float* __restrict__ bb, const float* __restrict__ mm,
    const float* __restrict__ vv,
    bf16_t* __restrict__ Yb, float* __restrict__ Yf,
    const int Lin, const int Lo, const int N)
{
  __shared__ __align__(16) bf16_t As[128 * 32];
  __shared__ __align__(16) bf16_t Bs[128 * 32];
  const int tid = threadIdx.x;
  const int wave = tid >> 6;
  const int lane = tid & 63;
  const int l0 = blockIdx.x * 128;
  const int n0 = blockIdx.y * 128;
  const int b = blockIdx.z;
  const int lm = lane & 15;
  const int quad = lane >> 4;
  const int wm = (wave >> 1) * 64;
  const int wn = (wave & 1) * 64;
  constexpr int Ktot = C * DIN;

  const int srow = wave * 32 + (lane >> 2);
  const int scol = (lane & 3) * 8;

  const int rA0 = min(l0 + srow, Lo - 1);
  const int rA1 = min(l0 + srow + 16, Lo - 1);

  const bf16_t* Xb = X + (size_t)b * Lin * DIN;
  const bf16_t* xg0 = Xb + (size_t)rA0 * DIN + scol;
  const bf16_t* xg1 = Xb + (size_t)rA1 * DIN + scol;
  const bf16_t* wg0 = W + (size_t)(n0 + srow) * Ktot + scol;
  const bf16_t* wg1 = W + (size_t)(n0 + srow + 16) * Ktot + scol;

  bf16_t* AsW = &As[(wave * 32) * 32];
  bf16_t* BsW = &Bs[(wave * 32) * 32];

  f32x4 acc[4][4];
  f32x4 zz = {};
  #pragma unroll
  for (int i = 0; i < 4; ++i)
    #pragma unroll
    for (int j = 0; j < 4; ++j) acc[i][j] = zz;

  for (int tap = 0; tap < C; ++tap) {
    const bf16_t* xa0 = xg0 + (size_t)tap * DIL * DIN;
    const bf16_t* xa1 = xg1 + (size_t)tap * DIL * DIN;
    const bf16_t* wa0 = wg0 + tap * DIN;
    const bf16_t* wa1 = wg1 + tap * DIN;
    for (int kc = 0; kc < DIN / 32; ++kc) {
      gload16(xa0 + kc * 32, AsW);
      gload16(xa1 + kc * 32, AsW + 16 * 32);
      gload16(wa0 + kc * 32, BsW);
      gload16(wa1 + kc * 32, BsW + 16 * 32);
      __syncthreads();
      bf16x8 av[4], bv[4];
      #pragma unroll
      for (int mt = 0; mt < 4; ++mt)
        av[mt] = *(const bf16x8*)&As[(wm + mt * 16 + lm) * 32 + quad * 8];
      #pragma unroll
      for (int nt = 0; nt < 4; ++nt)
        bv[nt] = *(const bf16x8*)&Bs[(wn + nt * 16 + lm) * 32 + quad * 8];
      #pragma unroll
      for (int mt = 0; mt < 4; ++mt)
        #pragma unroll
        for (int nt = 0; nt < 4; ++nt)
          acc[mt][nt] = __builtin_amdgcn_mfma_f32_16x16x32_bf16(av[mt], bv[nt], acc[mt][nt], 0, 0, 0);
      __syncthreads();
    }
  }

  #pragma unroll
  for (int nt = 0; nt < 4; ++nt) {
    const int col = n0 + wn + nt * 16 + lm;
    const float sc = gg[col] * rsqrtf(vv[col] + EPSBN);
    const float sh = bb[col] - mm[col] * sc;
    const float bi = bias[col];
    #pragma unroll
    for (int mt = 0; mt < 4; ++mt) {
      const int rbase = l0 + wm + mt * 16 + quad * 4;
      #pragma unroll
      for (int r = 0; r < 4; ++r) {
        const int row = rbase + r;
        if (row < Lo) {
          float val = fmaxf(acc[mt][nt][r] + bi, 0.0f) * sc + sh;
          const size_t oi = ((size_t)b * Lo + row) * N + col;
          if constexpr (OUTF32) Yf[oi] = val;
          else                  Yb[oi] = (bf16_t)val;
        }
      }
    }
  }
}

// ---------------- gi0 = act5 @ wih0^T + bih0, fp32; n-gate rows (32..47) pre-scaled x2 ----------------
__global__ __launch_bounds__(256, 2) void gi0_kernel(
    const float* __restrict__ A5, const float* __restrict__ wih,
    const float* __restrict__ bih, float* __restrict__ GI, const int T)
{
  __shared__ __align__(16) float Xs[64 * 132];
  __shared__ __align__(16) float Ws[48 * 132];
  const int tid = threadIdx.x;
  const int b = blockIdx.y, t0 = blockIdx.x * 64;
  for (int c = tid; c < 48 * 32; c += 256) {
    int j = c >> 5, k4 = c & 31;
    *(float4*)&Ws[j * 132 + k4 * 4] = *(const float4*)&wih[j * 128 + k4 * 4];
  }
  for (int c = tid; c < 64 * 32; c += 256) {
    int r = c >> 5, k4 = c & 31;
    int tt = min(t0 + r, T - 1);
    *(float4*)&Xs[r * 132 + k4 * 4] = *(const float4*)&A5[((size_t)b * T + tt) * 128 + k4 * 4];
  }
  __syncthreads();
  const int tl = tid >> 2, jg = tid & 3;
  float acc[12];
  #pragma unroll
  for (int i = 0; i < 12; ++i) acc[i] = 0.0f;
  for (int k = 0; k < 128; k += 4) {
    float4 xv = *(const float4*)&Xs[tl * 132 + k];
    #pragma unroll
    for (int jj = 0; jj < 12; ++jj) {
      float4 wv = *(const float4*)&Ws[(jg * 12 + jj) * 132 + k];
      acc[jj] += xv.x * wv.x + xv.y * wv.y + xv.z * wv.z + xv.w * wv.w;
    }
  }
  const int t = t0 + tl;
  if (t < T) {
    float* dst = &GI[((size_t)b * T + t) * 48 + jg * 12];
    #pragma unroll
    for (int jj = 0; jj < 12; ++jj) {
      const int row = jg * 12 + jj;
      const float s = (row >= 32) ? 2.0f : 1.0f;   // fold tanh's 2x into n-gate gi
      dst[jj] = (acc[jj] + bih[row]) * s;
    }
  }
}

// ---------------- GRU weight packing: gate-split per-lane layout ----------------
// Lane l = q*16+u (q = gate r/z/n). Per lane: chainA = whh0 row l, chainB = wih1 row l,
// chainC = whh1 row l (f16, n-rows pre-scaled x2). Biases kept separate (b_hn needs r-mult).
__global__ __launch_bounds__(64) void pack_gru(
    const float* __restrict__ whh0, const float* __restrict__ bhh0,
    const float* __restrict__ wih1, const float* __restrict__ bih1,
    const float* __restrict__ whh1, const float* __restrict__ bhh1,
    __fp16* __restrict__ WP, float* __restrict__ BP)
{
  const int l = threadIdx.x;
  if (l >= 48) return;
  const float sc = (l >= 32) ? 2.0f : 1.0f;
  #pragma unroll
  for (int k = 0; k < 16; ++k) {
    WP[l * 48 + k]      = (__fp16)(whh0[l * 16 + k] * sc);
    WP[l * 48 + 16 + k] = (__fp16)(wih1[l * 16 + k] * sc);
    WP[l * 48 + 32 + k] = (__fp16)(whh1[l * 16 + k] * sc);
  }
  BP[l * 4 + 0] = bhh0[l] * sc;
  BP[l * 4 + 1] = bih1[l] * sc;
  BP[l * 4 + 2] = bhh1[l] * sc;
  BP[l * 4 + 3] = 0.0f;
}

// ---------------- fused 2-layer GRU: gate-split lanes, 24 dot2/step ----------------
// Lane q*16+u owns gate q of unit u for BOTH layers: dA = whh0_q[u]·h0 (L0),
// dB = wih1_q[u]·h0 (L1 input), dC = whh1_q[u]·h1 (L1 recurrent). Phase1: sigma on
// all lanes (valid on q0=r, q1=z). 4 shfl_xor deliver r/z to q2 lanes, which compute
// n + the h updates (state lives on lanes 32..47). Broadcast: DPP pack + 16 readlanes.
// L1 runs one step behind L0 (consumes previous broadcast). Weights are pinned in
// VGPRs by an empty asm with "+v" constraints (defeats load rematerialization).
__global__ __launch_bounds__(64, 1) void gru_kernel(
    const float* __restrict__ GI, const __fp16* __restrict__ WP,
    const float* __restrict__ BP, float* __restrict__ out, const int T)
{
  const int b = blockIdx.x;
  const int lane = threadIdx.x;
  const int l48 = min(lane, 47);
  const int u = lane & 15;
  const bool isq2 = (lane >= 32) && (lane < 48);
  const bool par = (lane & 1) != 0;

  const __fp16* wl = WP + (size_t)l48 * 48;
  const i32x4 va0 = *(const i32x4*)(wl + 0);
  const i32x4 va1 = *(const i32x4*)(wl + 8);
  const i32x4 vb0 = *(const i32x4*)(wl + 16);
  const i32x4 vb1 = *(const i32x4*)(wl + 24);
  const i32x4 vc0 = *(const i32x4*)(wl + 32);
  const i32x4 vc1 = *(const i32x4*)(wl + 40);
  int wA[8] = {va0.x, va0.y, va0.z, va0.w, va1.x, va1.y, va1.z, va1.w};
  int wB[8] = {vb0.x, vb0.y, vb0.z, vb0.w, vb1.x, vb1.y, vb1.z, vb1.w};
  int wC[8] = {vc0.x, vc0.y, vc0.z, vc0.w, vc1.x, vc1.y, vc1.z, vc1.w};
  const float4 bvv = *(const float4*)(BP + (size_t)l48 * 4);
  float biasA = bvv.x, biasB = bvv.y, biasC = bvv.z;

  const float* gib = GI + (size_t)b * T * 48 + l48;
  float g0 = gib[0], g1 = gib[48], g2 = gib[96];
  const int Tm1 = T - 1;

  int s0[8], s1[8];
  #pragma unroll
  for (int m = 0; m < 8; ++m) { s0[m] = 0; s1[m] = 0; }
  float H0 = 0.0f, H1 = 0.0f;
  float* outp = out + (size_t)b * T * 16 + u;

  #pragma unroll 3
  for (int i = 0; i <= T; ++i) {
    // pin weights+biases live in VGPRs across the loop (no rematerialization)
    asm volatile("" :
      "+v"(wA[0]), "+v"(wA[1]), "+v"(wA[2]), "+v"(wA[3]),
      "+v"(wA[4]), "+v"(wA[5]), "+v"(wA[6]), "+v"(wA[7]),
      "+v"(wB[0]), "+v"(wB[1]), "+v"(wB[2]), "+v"(wB[3]),
      "+v"(wB[4]), "+v"(wB[5]), "+v"(wB[6]), "+v"(wB[7]),
      "+v"(wC[0]), "+v"(wC[1]), "+v"(wC[2]), "+v"(wC[3]),
      "+v"(wC[4]), "+v"(wC[5]), "+v"(wC[6]), "+v"(wC[7]),
      "+v"(biasA), "+v"(biasB), "+v"(biasC));

    const int tp = min(i + 3, Tm1);
    const float g3 = gib[(size_t)tp * 48];

    float dA = 0.0f, dB = 0.0f, dC = 0.0f;
    #pragma unroll
    for (int m = 0; m < 8; ++m) {
      dA = dot2i(wA[m], s0[m], dA);
      dB = dot2i(wB[m], s0[m], dB);
      dC = dot2i(wC[m], s1[m], dC);
    }
    const float dAa = dA + biasA;      // whh0·h0 + bhh0   (x2 on n-lanes)
    const float dBb = dB + biasB;      // wih1·h0 + bih1
    const float dCc = dC + biasC;      // whh1·h1 + bhh1
    const float preX = g0 + dAa;       // L0 r/z pre-activation (gi includes bih0)
    const float preY = dBb + dCc;      // L1 r/z pre-activation
    const float tX = 1.0f / (1.0f + __expf(-preX));
    const float tY = 1.0f / (1.0f + __expf(-preY));

    const float rXs = __shfl_xor(tX, 32);   // on q2 lane 32+u: r0[u] from lane u
    const float rYs = __shfl_xor(tY, 32);   // r1[u]
    const float zXs = __shfl_xor(tX, 48);   // on q2 lane 32+u: z0[u] from lane 16+u
    const float zYs = __shfl_xor(tY, 48);   // z1[u]

    // n-gates (valid on q2 lanes; weights/bias/gi pre-scaled x2 there)
    const float p2X = fmaf(rXs, dAa, g0);
    const float p2Y = fmaf(rYs, dCc, dBb);
    const float eX = __expf(p2X);
    const float eY = __expf(p2Y);
    const float t2X = 1.0f / (eX + 1.0f);
    const float t2Y = 1.0f / (eY + 1.0f);
    const float nX = fmaf(t2X, -2.0f, 1.0f);   // tanh
    const float nY = fmaf(t2Y, -2.0f, 1.0f);
    const float H0n = fmaf(zXs, H0 - nX, nX);
    float H1n = fmaf(zYs, H1 - nY, nY);
    if (i == 0) H1n = 0.0f;                    // L1 pipeline warm-up: h1(-1)=0
    H0 = H0n; H1 = H1n;

    if (i > 0 && isq2) outp[(size_t)(i - 1) * 16] = H1n;

    // broadcast h0(i), h1(i-1) from lanes 32..47 as packed f16 pairs
    const int h0i = __float_as_int(H0n);
    const int h1i = __float_as_int(H1n);
#if __has_builtin(__builtin_amdgcn_mov_dpp)
    const int nb0 = __builtin_amdgcn_mov_dpp(h0i, 0xB1, 0xF, 0xF, true);
    const int nb1 = __builtin_amdgcn_mov_dpp(h1i, 0xB1, 0xF, 0xF, true);
#else
    const int nb0 = __shfl_xor(h0i, 1);
    const int nb1 = __shfl_xor(h1i, 1);
#endif
    const float lo0 = par ? __int_as_float(nb0) : H0n;
    const float hi0 = par ? H0n : __int_as_float(nb0);
    const float lo1 = par ? __int_as_float(nb1) : H1n;
    const float hi1 = par ? H1n : __int_as_float(nb1);
    const int pk0 = h2i(__builtin_amdgcn_cvt_pkrtz(lo0, hi0));
    const int pk1 = h2i(__builtin_amdgcn_cvt_pkrtz(lo1, hi1));
    #pragma unroll
    for (int m = 0; m < 8; ++m) {
      s0[m] = __builtin_amdgcn_readlane(pk0, 32 + 2 * m);
      s1[m] = __builtin_amdgcn_readlane(pk1, 32 + 2 * m);
    }

    g0 = g1; g1 = g2; g2 = g3;
  }
}

extern "C" void kernel_launch(void* const* d_in, const int* in_sizes, int n_in,
                              void* d_out, int out_size, void* d_ws, size_t ws_size,
                              hipStream_t stream) {
  (void)in_sizes; (void)n_in; (void)out_size; (void)ws_size;
  const float* x = (const float*)d_in[0];
  const float* w1 = (const float*)d_in[1];  const float* b1 = (const float*)d_in[2];
  const float* g1 = (const float*)d_in[3];  const float* bb1 = (const float*)d_in[4];
  const float* m1 = (const float*)d_in[5];  const float* v1 = (const float*)d_in[6];
  const float* w2 = (const float*)d_in[7];  const float* b2 = (const float*)d_in[8];
  const float* g2 = (const float*)d_in[9];  const float* bb2 = (const float*)d_in[10];
  const float* m2 = (const float*)d_in[11]; const float* v2 = (const float*)d_in[12];
  const float* w3 = (const float*)d_in[13]; const float* b3 = (const float*)d_in[14];
  const float* g3 = (const float*)d_in[15]; const float* bb3 = (const float*)d_in[16];
  const float* m3 = (const float*)d_in[17]; const float* v3 = (const float*)d_in[18];
  const float* w4 = (const float*)d_in[19]; const float* b4 = (const float*)d_in[20];
  const float* g4 = (const float*)d_in[21]; const float* bb4 = (const float*)d_in[22];
  const float* m4 = (const float*)d_in[23]; const float* v4 = (const float*)d_in[24];
  const float* w5 = (const float*)d_in[25]; const float* b5 = (const float*)d_in[26];
  const float* g5 = (const float*)d_in[27]; const float* bb5 = (const float*)d_in[28];
  const float* m5 = (const float*)d_in[29]; const float* v5 = (const float*)d_in[30];
  const float* wih0 = (const float*)d_in[31];
  const float* whh0 = (const float*)d_in[32];
  const float* bih0 = (const float*)d_in[33];
  const float* bhh0 = (const float*)d_in[34];
  const float* wih1 = (const float*)d_in[35];
  const float* whh1 = (const float*)d_in[36];
  const float* bih1 = (const float*)d_in[37];
  const float* bhh1 = (const float*)d_in[38];

  char* ws = (char*)d_ws;
  size_t off = 0;
  auto alloc = [&](size_t bytes) {
    size_t r = off;
    off = (off + bytes + 255) & ~(size_t)255;
    return r;
  };
  __fp16* WPg = (__fp16*)(ws + alloc((size_t)48 * 48 * 2));
  float*  BPg = (float*)(ws + alloc((size_t)48 * 4 * 4));
  bf16_t* p1 = (bf16_t*)(ws + alloc((size_t)256 * 160 * 2));
  bf16_t* p2 = (bf16_t*)(ws + alloc((size_t)512 * 1280 * 2));
  bf16_t* p3 = (bf16_t*)(ws + alloc((size_t)256 * 2560 * 2));
  bf16_t* p4 = (bf16_t*)(ws + alloc((size_t)128 * 768 * 2));
  bf16_t* p5 = (bf16_t*)(ws + alloc((size_t)128 * 384 * 2));
  bf16_t* xp = (bf16_t*)(ws + alloc((size_t)32 * 4096 * 32 * 2));
  char* bufA = ws + alloc((size_t)32 * 4076 * 256 * 2);
  char* bufB = ws + alloc((size_t)32 * 4056 * 512 * 2);

  bf16_t* a1 = (bf16_t*)bufA;
  bf16_t* a2 = (bf16_t*)bufB;
  bf16_t* a3 = (bf16_t*)bufA;
  bf16_t* a4 = (bf16_t*)bufB;
  float*  a5 = (float*)bufA;
  float*  gi = (float*)bufB;

  hipLaunchKernelGGL(pack_w_kernel, dim3(2560, 5), dim3(256), 0, stream,
                     w1, w2, w3, w4, w5, p1, p2, p3, p4, p5);
  hipLaunchKernelGGL(pack_x_kernel, dim3(16, 32), dim3(256), 0, stream, x, xp);
  hipLaunchKernelGGL(pack_gru, dim3(1), dim3(64), 0, stream,
                     whh0, bhh0, wih1, bih1, whh1, bhh1, WPg, BPg);

  hipLaunchKernelGGL((tdnn_gemm<32, 5, 5, false>), dim3(32, 2, 32), dim3(256), 0, stream,
                     xp, p1, b1, g1, bb1, m1, v1, a1, (float*)nullptr, 4096, 4076, 256);
  hipLaunchKernelGGL((tdnn_gemm<256, 5, 5, false>), dim3(32, 4, 32), dim3(256), 0, stream,
                     a1, p2, b2, g2, bb2, m2, v2, a2, (float*)nullptr, 4076, 4056, 512);
  hipLaunchKernelGGL((tdnn_gemm<512, 5, 5, false>), dim3(32, 2, 32), dim3(256), 0, stream,
                     a2, p3, b3, g3, bb3, m3, v3, a3, (float*)nullptr, 4056, 4036, 256);
  hipLaunchKernelGGL((tdnn_gemm<256, 3, 3, false>), dim3(32, 1, 32), dim3(256), 0, stream,
                     a3, p4, b4, g4, bb4, m4, v4, a4, (float*)nullptr, 4036, 4030, 128);
  hipLaunchKernelGGL((tdnn_gemm<128, 3, 3, true>), dim3(32, 1, 32), dim3(256), 0, stream,
                     a4, p5, b5, g5, bb5, m5, v5, (bf16_t*)nullptr, a5, 4030, 4024, 128);

  hipLaunchKernelGGL(gi0_kernel, dim3(63, 32), dim3(256), 0, stream, a5, wih0, bih0, gi, 4024);
  hipLaunchKernelGGL(gru_kernel, dim3(32), dim3(64), 0, stream,
                     gi, WPg, BPg, (float*)d_out, 4024);
}